// Round 2
// baseline (248.959 us; speedup 1.0000x reference)
//
#include <hip/hip_runtime.h>
#include <stdint.h>

// Problem constants
#define NROWS 16384   // B*H*W = 16*32*32
#define KENT  8192    // codebook entries
#define CDIM  256     // embedding dim
#define NELEM 4194304 // B*H*W*C elements of z / z_q

// int8 screen scales: z*22 (clamp +-127 = 5.77 sigma), cb*127*8192 (<=0.5 LSB)
#define ZSCALE 22.0f
#define ESCALE 1040384.0f      // 127*8192, exact in fp32
#define MARGIN_INT 4096        // = 1.79e-4 real ~ 8 sigma of i8-quant error
#define SBIAS 4194304          // 1<<22, |score| <= 256*127*127 = 4129024 < SBIAS

// ws layout (bytes):
//   [0,        4194304): zbi8   i8[4M]   z int8, k-major tile layout
//   [4194304,  6291456): cbi8   i8[2M]   codebook int8, same layout
//   [6291456, 23068672): gstats u64[128][16384]  per (64-entry cb group, row):
//                        (top1 << 32) | top2, packed (score+SBIAS)<<6 | col6
//   [23068672,23134208): z2w   float[16384]  np-tree row norms

typedef int v4i __attribute__((ext_vector_type(4)));

__device__ inline int q8(float x, float s) {
    int v = __float2int_rn(x * s);
    return v < -127 ? -127 : (v > 127 ? 127 : v);
}
__device__ inline unsigned pk4(int a, int b, int c, int d) {
    return (a & 255) | ((b & 255) << 8) | ((c & 255) << 16) | ((d & 255) << 24);
}
__device__ inline unsigned umax_(unsigned a, unsigned b) { return a > b ? a : b; }
__device__ inline unsigned umin_(unsigned a, unsigned b) { return a < b ? a : b; }
__device__ inline void gload_lds16(const void* g, void* l) {
    __builtin_amdgcn_global_load_lds(
        (const __attribute__((address_space(1))) void*)g,
        (__attribute__((address_space(3))) void*)l, 16, 0, 0);
}

// ---------------------------------------------------------------------------
// Fused prep: blocks 0..255 = prep_z (VALIDATED np-tree z2 + i8 tile store),
// blocks 256..319 = prep_cb (i8), plus loss init.
__global__ __launch_bounds__(128) void vq_prep(
        const float* __restrict__ z, const float* __restrict__ cb,
        float* __restrict__ z2w, char* __restrict__ zbi8,
        char* __restrict__ cbbi8, float* __restrict__ loss_out) {
    const int t = threadIdx.x;
    const int bid = blockIdx.x;

    if (bid >= 256) {   // ---- prep_cb: panel p, one codebook row per thread
        const int p = bid - 256, n0 = p * 128;
        char* dst = cbbi8 + p * 32768;
        const float* src = cb + (n0 + t) * 256;
#pragma unroll
        for (int q = 0; q < 16; ++q) {
            float4 a = *(const float4*)(src + q * 16);
            float4 b = *(const float4*)(src + q * 16 + 4);
            float4 c = *(const float4*)(src + q * 16 + 8);
            float4 d = *(const float4*)(src + q * 16 + 12);
            uint4 v;
            v.x = pk4(q8(a.x,ESCALE), q8(a.y,ESCALE), q8(a.z,ESCALE), q8(a.w,ESCALE));
            v.y = pk4(q8(b.x,ESCALE), q8(b.y,ESCALE), q8(b.z,ESCALE), q8(b.w,ESCALE));
            v.z = pk4(q8(c.x,ESCALE), q8(c.y,ESCALE), q8(c.z,ESCALE), q8(c.w,ESCALE));
            v.w = pk4(q8(d.x,ESCALE), q8(d.y,ESCALE), q8(d.z,ESCALE), q8(d.w,ESCALE));
            *(uint4*)&dst[(q * 128 + t) * 16] = v;
        }
        if (p == 0 && t == 0) loss_out[0] = 0.f;
        return;
    }

    // ---- prep_z: 2 threads/row, one per 128-c half of the np tree
    __shared__ float s64[64];
    const int r = t & 63;
    const int blk = t >> 6;
    const int n = bid * 64 + r;
    const int b = n >> 10, hw = n & 1023;
    const float* base = z + b * 262144 + hw;

    const int p = n >> 7, rp = n & 127;
    char* dst = zbi8 + p * 32768;

    float t0[16], p01[16], p0123[16], C[16];

#pragma unroll
    for (int j = 0; j < 8; ++j) {
        float a[16];
#pragma unroll
        for (int L = 0; L < 16; ++L)
            a[L] = base[(blk * 128 + L + 16 * j) * 1024];
        int qb[16];
#pragma unroll
        for (int L = 0; L < 16; ++L) {
            qb[L] = q8(a[L], ZSCALE);
            float sq = a[L] * a[L];
            asm volatile("" : "+v"(sq));   // forbid FMA contraction into adds
            // np tree phases: C = ((q0+q1)+(q2+q3)) + ((q4+q5)+(q6+q7))
            if (j == 0 || j == 2 || j == 4 || j == 6) t0[L] = sq;
            else if (j == 1) p01[L] = t0[L] + sq;
            else if (j == 3) p0123[L] = p01[L] + (t0[L] + sq);
            else if (j == 5) p01[L] = t0[L] + sq;                 // p45
            else             C[L] = p0123[L] + (p01[L] + (t0[L] + sq));
        }
        uint4 v;
        v.x = pk4(qb[0], qb[1], qb[2], qb[3]);
        v.y = pk4(qb[4], qb[5], qb[6], qb[7]);
        v.z = pk4(qb[8], qb[9], qb[10], qb[11]);
        v.w = pk4(qb[12], qb[13], qb[14], qb[15]);
        *(uint4*)&dst[((blk * 8 + j) * 128 + rp) * 16] = v;
    }
    float t8[8];
#pragma unroll
    for (int L = 0; L < 8; ++L) t8[L] = C[L] + C[L + 8];
    float t4[4];
#pragma unroll
    for (int L = 0; L < 4; ++L) t4[L] = t8[L] + t8[L + 4];
    float t2a = t4[0] + t4[2];
    float t2b = t4[1] + t4[3];
    float bs = t2a + t2b;

    if (blk == 1) s64[r] = bs;
    __syncthreads();
    if (blk == 0) z2w[n] = bs + s64[r];
}

// ---------------------------------------------------------------------------
// int8 MFMA screen v7: SWAPPED operands -- mfma(cb, z) -- so each z-row's
// scores land lane-local (16 per lane across i,g regs): top-2 is a register
// tree + 2-step q4 butterfly (16 shfl/wave vs 64). Block processes 4 pn
// panels per A-staging (one drain per 4 K-loops); next panel's cb fragments
// prefetched during the epilogue VALU phase.
__global__ __launch_bounds__(256, 4) void vq_gemm(
        const char* __restrict__ zbi8,
        const char* __restrict__ cbbi8,
        unsigned long long* __restrict__ gstats) {
    __shared__ __align__(16) char smem[32768];   // A (z) panel

    const int tid = threadIdx.x;
    const int w = tid >> 6, l = tid & 63;
    const int q4 = l >> 4, cl = l & 15;
    const int mw = w & 1, nw = w >> 1;   // mw: cb 64-half, nw: z 64-half

    // XCD-locality swizzle: per XCD, pm fast (16), pnq slow (16)
    const unsigned bx = blockIdx.x;
    const unsigned xcd = bx & 7, local = bx >> 3;       // local in [0,256)
    const unsigned pm  = (local & 15) * 8 + xcd;        // [0,128)
    const unsigned pnq = local >> 4;                    // [0,16), 4 pn each

    const char* Ab = zbi8 + pm * 32768;

    // stage whole A panel: 8 issues x 256 thr x 16B = 32KB
#pragma unroll
    for (int u = 0; u < 8; ++u)
        gload_lds16(Ab + u * 4096 + tid * 16, smem + u * 4096 + (w << 10));

    // cb fragment stream base: i via +256, kt via +8192, pn via +32768
    const char* ab0 = cbbi8 + (pnq * 4) * 32768
                            + (q4 * 128 + mw * 64 + cl) * 16;
    v4i af[4], afn[4];
#pragma unroll
    for (int i = 0; i < 4; ++i)
        af[i] = *(const v4i*)(ab0 + i * 256);

    const unsigned vb = ((unsigned)SBIAS << 6) + (unsigned)(q4 * 4);

    __syncthreads();   // single A-staging drain (af prologue rides along)

    for (int p = 0; p < 4; ++p) {
        v4i acc[4][4];
#pragma unroll
        for (int kt = 0; kt < 4; ++kt) {
            v4i bfl[4];
#pragma unroll
            for (int j = 0; j < 4; ++j)
                bfl[j] = *(const v4i*)(smem + kt * 8192 + q4 * 2048
                                            + nw * 1024 + j * 256 + cl * 16);
            if (p < 3 || kt < 3) {   // (kt+1)*8192 rolls into next panel at kt=3
                const char* nxt = ab0 + p * 32768 + (kt + 1) * 8192;
#pragma unroll
                for (int i = 0; i < 4; ++i)
                    afn[i] = *(const v4i*)(nxt + i * 256);
            }
#pragma unroll
            for (int i = 0; i < 4; ++i)
#pragma unroll
                for (int j = 0; j < 4; ++j) {
                    if (kt == 0)
                        acc[i][j] = __builtin_amdgcn_mfma_i32_16x16x64_i8(
                            af[i], bfl[j], (v4i)0, 0, 0, 0);
                    else
                        acc[i][j] = __builtin_amdgcn_mfma_i32_16x16x64_i8(
                            af[i], bfl[j], acc[i][j], 0, 0, 0);
                }
#pragma unroll
            for (int i = 0; i < 4; ++i) af[i] = afn[i];
        }

        // ---- epilogue: per z-row lane-local top-2 over this wave's 64 cb --
        // acc[i][j][g]: cb = mw*64 + i*16 + q4*4 + g, z-row = nw*64 + j*16 + cl
        const unsigned pn = pnq * 4 + (unsigned)p;
        unsigned long long* gs = gstats + (pn * 2 + (unsigned)mw) * 16384u
                                        + pm * 128u + (unsigned)(nw * 64);
#pragma unroll
        for (int jj = 0; jj < 4; ++jj) {
            unsigned m1[8], m2[8];
#pragma unroll
            for (int i = 0; i < 4; ++i)
#pragma unroll
                for (int gp = 0; gp < 2; ++gp) {
                    unsigned pa = ((unsigned)acc[i][jj][2 * gp] << 6)
                                  + vb + (unsigned)(i * 16 + 2 * gp);
                    unsigned pb = ((unsigned)acc[i][jj][2 * gp + 1] << 6)
                                  + vb + (unsigned)(i * 16 + 2 * gp + 1);
                    m1[i * 2 + gp] = umax_(pa, pb);
                    m2[i * 2 + gp] = umin_(pa, pb);
                }
#pragma unroll
            for (int s = 4; s >= 1; s >>= 1)
#pragma unroll
                for (int u = 0; u < 4; ++u) {
                    if (u < s) {
                        unsigned a1 = m1[u], a2 = m2[u];
                        unsigned b1 = m1[u + s], b2 = m2[u + s];
                        m1[u] = umax_(a1, b1);
                        m2[u] = umax_(umin_(a1, b1), umax_(a2, b2));
                    }
                }
            unsigned t1 = m1[0], t2 = m2[0];
#pragma unroll
            for (int off = 16; off <= 32; off <<= 1) {
                unsigned o1 = (unsigned)__shfl_xor((int)t1, off);
                unsigned o2 = (unsigned)__shfl_xor((int)t2, off);
                t2 = umax_(umax_(t2, o2), umin_(t1, o1));
                t1 = umax_(t1, o1);
            }
            if (q4 == 0)
                gs[jj * 16 + cl] =
                    ((unsigned long long)t1 << 32) | (unsigned long long)t2;
        }
    }
}

// ---------------------------------------------------------------------------
// Finalize: rescore + scatter FUSED. 512 blocks x 32 rows = one scatter tile
// (b, j) each; indices never leave LDS. gstats entries kept in registers
// between max-derivation and candidate-gather (no 16MB L2 re-read).
__global__ __launch_bounds__(256) void vq_finalize(
        const float* __restrict__ z, const float* __restrict__ cb,
        const float* __restrict__ z2w,
        const unsigned long long* __restrict__ gstats,
        float* __restrict__ out, float* __restrict__ out_idx) {
    __shared__ float zs[32][32];
    __shared__ unsigned pmax[8][32];
    __shared__ int thrL[32];
    __shared__ unsigned candL[512];    // (r<<13)|k
    __shared__ unsigned blkcnt;
    __shared__ unsigned long long bestL[32];
    __shared__ float tile[32 * 257];   // scatter tile, stride 257 floats

    const int t = threadIdx.x;
    const int bid = blockIdx.x;
    const int n0 = bid * 32;
    const int b = bid >> 5, j = bid & 31;
    const int hw0 = j * 32;
    const int r = t & 31, gc = t >> 5;   // gc in [0,8): 16 groups each

    // phase 1: per-row max of group top1s (= exact global row max); keep e[]
    unsigned long long e[16];
    unsigned m = 0;
#pragma unroll
    for (int g2 = 0; g2 < 16; ++g2) {
        e[g2] = gstats[(size_t)(gc * 16 + g2) * 16384u + (unsigned)(n0 + r)];
        m = umax_(m, (unsigned)(e[g2] >> 32));
    }
    pmax[gc][r] = m;
    if (t == 0) blkcnt = 0;
    __syncthreads();
    if (t < 32) {
        unsigned mm = 0;
#pragma unroll
        for (int g = 0; g < 8; ++g) mm = umax_(mm, pmax[g][t]);
        thrL[t] = (int)(mm >> 6) - MARGIN_INT;   // biased domain both sides
        bestL[t] = ~0ull;
    }
    __syncthreads();

    // phase 2: candidates = group top-1/top-2 entries >= threshold
    {
        int th = thrL[r];
#pragma unroll
        for (int g2 = 0; g2 < 16; ++g2) {
            unsigned p1 = (unsigned)(e[g2] >> 32), p2 = (unsigned)e[g2];
            unsigned kb = (unsigned)(gc * 16 + g2) * 64u;
            if ((int)(p1 >> 6) >= th) {
                unsigned pos = atomicAdd(&blkcnt, 1u);
                if (pos < 512u)
                    candL[pos] = ((unsigned)r << 13) | (kb + (p1 & 63u));
            }
            if ((int)(p2 >> 6) >= th) {
                unsigned pos = atomicAdd(&blkcnt, 1u);
                if (pos < 512u)
                    candL[pos] = ((unsigned)r << 13) | (kb + (p2 & 63u));
            }
        }
    }
    __syncthreads();
    int ns = (int)(blkcnt < 512u ? blkcnt : 512u);

    for (int base = 0; base < ns; base += 256) {
        bool active = base + t < ns;
        int rr0 = 0, k = 0;
        if (active) {
            unsigned v = candL[base + t];
            rr0 = v >> 13; k = v & 8191;
        }
        float sacc = 0.f;
        for (int ch = 0; ch < 8; ++ch) {
            __syncthreads();
            {   // stage 32 channels x 32 rows, coalesced
                int rr = t & 31, cc2 = t >> 5;
#pragma unroll
                for (int u = 0; u < 4; ++u) {
                    int cc = u * 8 + cc2;
                    zs[cc][rr] = z[b * 262144 + (ch * 32 + cc) * 1024 + hw0 + rr];
                }
            }
            __syncthreads();
            if (active) {
                const float4* cbp = (const float4*)(cb + k * 256 + ch * 32);
                float4 A0 = cbp[0], A1 = cbp[1], A2 = cbp[2], A3 = cbp[3];
                float4 A4 = cbp[4], A5 = cbp[5], A6 = cbp[6], A7 = cbp[7];
                float Af[32] = {A0.x,A0.y,A0.z,A0.w, A1.x,A1.y,A1.z,A1.w,
                                A2.x,A2.y,A2.z,A2.w, A3.x,A3.y,A3.z,A3.w,
                                A4.x,A4.y,A4.z,A4.w, A5.x,A5.y,A5.z,A5.w,
                                A6.x,A6.y,A6.z,A6.w, A7.x,A7.y,A7.z,A7.w};
#pragma unroll
                for (int u = 0; u < 32; ++u)
                    sacc = __builtin_fmaf(zs[u][rr0], Af[u], sacc);
            }
        }
        if (active) {
            float d = z2w[n0 + rr0] - 2.0f * sacc;   // single rounding, d > 0
            unsigned long long key =
                ((unsigned long long)__float_as_uint(d) << 32) | (unsigned)k;
            atomicMin(&bestL[rr0], key);
        }
    }
    __syncthreads();
    if (t < 32)
        out_idx[n0 + t] = (float)(unsigned)(bestL[t] & 0xFFFFFFFFu);

    // ---- fused scatter: gather 32 winning cb rows, write out k-coalesced --
    {
        const int c0 = t & 63;
        const int w0 = (t >> 6) * 8;
#pragma unroll
        for (int it = 0; it < 8; ++it) {
            int wr = w0 + it;
            int kk = (int)(unsigned)(bestL[wr] & 0xFFFFFFFFu);
            const float* src = cb + kk * 256 + c0;
            float* drow = tile + wr * 257 + c0;
            drow[0]   = src[0];
            drow[64]  = src[64];
            drow[128] = src[128];
            drow[192] = src[192];
        }
    }
    __syncthreads();

    float* obase = out + b * 262144 + j * 256;
    const int wv = t >> 3, cb8 = (t & 7) * 32;
#pragma unroll
    for (int it = 0; it < 32; ++it)     // it = i; lane = k (coalesced store)
        obase[it * 8192 + t] = tile[wv * 257 + cb8 + it];
}

// ---------------------------------------------------------------------------
// Loss, block = (b, i): z read w-coalesced (staged), out re-read coalesced.
// loss += 1.25/N * sum((zp - zq)^2);  zp(o) = z[b,k,i,j], zq(o) = out[o].
__global__ __launch_bounds__(256) void vq_loss(
        const float* __restrict__ z, const float* __restrict__ out,
        float* __restrict__ loss_out) {
    __shared__ float zs[256][33];
    __shared__ float wsum[4];

    const int t = threadIdx.x;
    const int b = blockIdx.x >> 5, i = blockIdx.x & 31;

#pragma unroll
    for (int it = 0; it < 32; ++it) {
        int k = it * 8 + (t >> 5);
        zs[k][t & 31] = z[b * 262144 + k * 1024 + i * 32 + (t & 31)];
    }
    __syncthreads();

    const float* ob = out + b * 262144 + i * 8192;
    float lsum = 0.f;
#pragma unroll 4
    for (int it = 0; it < 32; ++it) {   // it = j; lane = k
        float d = zs[t][it] - ob[it * 256 + t];
        lsum = __builtin_fmaf(d, d, lsum);
    }
#pragma unroll
    for (int off = 32; off >= 1; off >>= 1) lsum += __shfl_down(lsum, off, 64);
    int lane = t & 63, wv = t >> 6;
    if (lane == 0) wsum[wv] = lsum;
    __syncthreads();
    if (t == 0)
        atomicAdd(loss_out, (wsum[0] + wsum[1] + wsum[2] + wsum[3]) *
                            (1.25f / (float)NELEM));
}

// ---------------------------------------------------------------------------
extern "C" void kernel_launch(void* const* d_in, const int* in_sizes, int n_in,
                              void* d_out, int out_size, void* d_ws, size_t ws_size,
                              hipStream_t stream) {
    const float* z  = (const float*)d_in[0];
    const float* cb = (const float*)d_in[1];
    float* out = (float*)d_out;

    char* ws = (char*)d_ws;
    char* zbi8               = ws;                                   // 4 MB
    char* cbbi8              = ws + 4194304;                         // 2 MB
    unsigned long long* gstats = (unsigned long long*)(ws + 6291456); // 16 MB
    float* z2w               = (float*)(ws + 23068672);

    vq_prep<<<320, 128, 0, stream>>>(z, cb, z2w, zbi8, cbbi8, out + NELEM);

    vq_gemm<<<2048, 256, 0, stream>>>(zbi8, cbbi8, gstats);

    vq_finalize<<<512, 256, 0, stream>>>(z, cb, z2w, gstats,
                                         out, out + NELEM + 1);

    vq_loss<<<512, 256, 0, stream>>>(z, out, out + NELEM);
}

// Round 3
// 153.045 us; speedup vs baseline: 1.6267x; 1.6267x over previous
//
#include <hip/hip_runtime.h>
#include <stdint.h>

// Problem constants
#define NROWS 16384   // B*H*W = 16*32*32
#define KENT  8192    // codebook entries
#define CDIM  256     // embedding dim
#define NELEM 4194304 // B*H*W*C elements of z / z_q

// int8 screen scales: z*22 (clamp +-127 = 5.77 sigma), cb*127*8192 (<=0.5 LSB)
#define ZSCALE 22.0f
#define ESCALE 1040384.0f      // 127*8192, exact in fp32
#define MARGIN_INT 4096        // = 1.79e-4 real ~ 8 sigma of i8-quant error
#define SBIAS 4194304          // 1<<22, |score| <= 256*127*127 = 4129024 < SBIAS

// ws layout (bytes):
//   [0,        4194304): zbi8   i8[4M]   z int8, k-major tile layout
//   [4194304,  6291456): cbi8   i8[2M]   codebook int8, same layout
//   [6291456, 23068672): gstats u64[128][16384]  per (64-entry cb group, row):
//                        (top1 << 32) | top2, packed (score+SBIAS)<<6 | col6
//   [23068672,23134208): z2w   float[16384]  np-tree row norms

typedef int v4i __attribute__((ext_vector_type(4)));

__device__ inline int q8(float x, float s) {
    int v = __float2int_rn(x * s);
    return v < -127 ? -127 : (v > 127 ? 127 : v);
}
__device__ inline unsigned pk4(int a, int b, int c, int d) {
    return (a & 255) | ((b & 255) << 8) | ((c & 255) << 16) | ((d & 255) << 24);
}
__device__ inline unsigned umax_(unsigned a, unsigned b) { return a > b ? a : b; }
__device__ inline unsigned umin_(unsigned a, unsigned b) { return a < b ? a : b; }
__device__ inline void gload_lds16(const void* g, void* l) {
    __builtin_amdgcn_global_load_lds(
        (const __attribute__((address_space(1))) void*)g,
        (__attribute__((address_space(3))) void*)l, 16, 0, 0);
}

// ---------------------------------------------------------------------------
// Fused prep: blocks 0..255 = prep_z (VALIDATED np-tree z2 + i8 tile store),
// blocks 256..319 = prep_cb (i8), plus loss init.
__global__ __launch_bounds__(128) void vq_prep(
        const float* __restrict__ z, const float* __restrict__ cb,
        float* __restrict__ z2w, char* __restrict__ zbi8,
        char* __restrict__ cbbi8, float* __restrict__ loss_out) {
    const int t = threadIdx.x;
    const int bid = blockIdx.x;

    if (bid >= 256) {   // ---- prep_cb: panel p, one codebook row per thread
        const int p = bid - 256, n0 = p * 128;
        char* dst = cbbi8 + p * 32768;
        const float* src = cb + (n0 + t) * 256;
#pragma unroll
        for (int q = 0; q < 16; ++q) {
            float4 a = *(const float4*)(src + q * 16);
            float4 b = *(const float4*)(src + q * 16 + 4);
            float4 c = *(const float4*)(src + q * 16 + 8);
            float4 d = *(const float4*)(src + q * 16 + 12);
            uint4 v;
            v.x = pk4(q8(a.x,ESCALE), q8(a.y,ESCALE), q8(a.z,ESCALE), q8(a.w,ESCALE));
            v.y = pk4(q8(b.x,ESCALE), q8(b.y,ESCALE), q8(b.z,ESCALE), q8(b.w,ESCALE));
            v.z = pk4(q8(c.x,ESCALE), q8(c.y,ESCALE), q8(c.z,ESCALE), q8(c.w,ESCALE));
            v.w = pk4(q8(d.x,ESCALE), q8(d.y,ESCALE), q8(d.z,ESCALE), q8(d.w,ESCALE));
            *(uint4*)&dst[(q * 128 + t) * 16] = v;
        }
        if (p == 0 && t == 0) loss_out[0] = 0.f;
        return;
    }

    // ---- prep_z: 2 threads/row, one per 128-c half of the np tree
    __shared__ float s64[64];
    const int r = t & 63;
    const int blk = t >> 6;
    const int n = bid * 64 + r;
    const int b = n >> 10, hw = n & 1023;
    const float* base = z + b * 262144 + hw;

    const int p = n >> 7, rp = n & 127;
    char* dst = zbi8 + p * 32768;

    float t0[16], p01[16], p0123[16], C[16];

#pragma unroll
    for (int j = 0; j < 8; ++j) {
        float a[16];
#pragma unroll
        for (int L = 0; L < 16; ++L)
            a[L] = base[(blk * 128 + L + 16 * j) * 1024];
        int qb[16];
#pragma unroll
        for (int L = 0; L < 16; ++L) {
            qb[L] = q8(a[L], ZSCALE);
            float sq = a[L] * a[L];
            asm volatile("" : "+v"(sq));   // forbid FMA contraction into adds
            // np tree phases: C = ((q0+q1)+(q2+q3)) + ((q4+q5)+(q6+q7))
            if (j == 0 || j == 2 || j == 4 || j == 6) t0[L] = sq;
            else if (j == 1) p01[L] = t0[L] + sq;
            else if (j == 3) p0123[L] = p01[L] + (t0[L] + sq);
            else if (j == 5) p01[L] = t0[L] + sq;                 // p45
            else             C[L] = p0123[L] + (p01[L] + (t0[L] + sq));
        }
        uint4 v;
        v.x = pk4(qb[0], qb[1], qb[2], qb[3]);
        v.y = pk4(qb[4], qb[5], qb[6], qb[7]);
        v.z = pk4(qb[8], qb[9], qb[10], qb[11]);
        v.w = pk4(qb[12], qb[13], qb[14], qb[15]);
        *(uint4*)&dst[((blk * 8 + j) * 128 + rp) * 16] = v;
    }
    float t8[8];
#pragma unroll
    for (int L = 0; L < 8; ++L) t8[L] = C[L] + C[L + 8];
    float t4[4];
#pragma unroll
    for (int L = 0; L < 4; ++L) t4[L] = t8[L] + t8[L + 4];
    float t2a = t4[0] + t4[2];
    float t2b = t4[1] + t4[3];
    float bs = t2a + t2b;

    if (blk == 1) s64[r] = bs;
    __syncthreads();
    if (blk == 0) z2w[n] = bs + s64[r];
}

// ---------------------------------------------------------------------------
// int8 MFMA screen v8: round-1's validated one-panel structure (grid 8192,
// whole z panel in LDS, ONE staging drain, 1-deep cb prefetch from L2) +
// round-2's validated SWAPPED operands -- mfma(cb, z) -- so each z-row's 64
// scores land lane-local (16/lane across i,g): top-2 is a register tree + 2
// shfl. 8 shfl/wave total vs 64. Fits the 128-reg unified cap of
// __launch_bounds__(256,4): acc 64 AGPR + ~56 VGPR (round-2's 4-panel
// variant spilled acc to scratch -> 560 MB HBM traffic; do NOT widen).
__global__ __launch_bounds__(256, 4) void vq_gemm(
        const char* __restrict__ zbi8,
        const char* __restrict__ cbbi8,
        unsigned long long* __restrict__ gstats) {
    __shared__ __align__(16) char smem[32768];   // z panel

    const int tid = threadIdx.x;
    const int w = tid >> 6, l = tid & 63;
    const int q4 = l >> 4, cl = l & 15;
    const int mw = w & 1, nw = w >> 1;   // mw: cb 64-half, nw: z 64-half

    // XCD-locality swizzle (validated r5): 16 pm x phased 16 pn per XCD
    const unsigned bx = blockIdx.x;
    const unsigned xcd = bx & 7, local = bx >> 3;
    const unsigned png = local >> 8;
    const unsigned rem = local & 255;
    const unsigned pm = (rem >> 4) * 8 + xcd;
    const unsigned pn = png * 16 + (rem & 15);

    const char* Ab = zbi8 + pm * 32768;
    const char* Bb = cbbi8 + pn * 32768;

    // stage whole z panel: 8 issues x 256 thr x 16B = 32KB
#pragma unroll
    for (int u = 0; u < 8; ++u)
        gload_lds16(Ab + u * 4096 + tid * 16, smem + u * 4096 + (w << 10));

    // cb fragments (MFMA A operand) streamed from L2: row = mw*64+i*16+cl,
    // kchunk = kt*4+q4; i via +256, kt via +8192
    const char* abase = Bb + (q4 * 128 + mw * 64 + cl) * 16;
    v4i af[4], afn[4];
#pragma unroll
    for (int i = 0; i < 4; ++i)
        af[i] = *(const v4i*)(abase + i * 256);

    const unsigned vb = ((unsigned)SBIAS << 6) + (unsigned)(q4 * 4);

    v4i acc[4][4];
    __syncthreads();   // single staging drain (af prologue rides along)

#pragma unroll
    for (int kt = 0; kt < 4; ++kt) {
        v4i bfl[4];
#pragma unroll
        for (int j = 0; j < 4; ++j)
            bfl[j] = *(const v4i*)(smem + kt * 8192 + q4 * 2048
                                        + nw * 1024 + j * 256 + cl * 16);
        if (kt < 3) {
#pragma unroll
            for (int i = 0; i < 4; ++i)
                afn[i] = *(const v4i*)(abase + (kt + 1) * 8192 + i * 256);
        }
#pragma unroll
        for (int i = 0; i < 4; ++i)
#pragma unroll
            for (int j = 0; j < 4; ++j) {
                if (kt == 0)
                    acc[i][j] = __builtin_amdgcn_mfma_i32_16x16x64_i8(
                        af[i], bfl[j], (v4i)0, 0, 0, 0);
                else
                    acc[i][j] = __builtin_amdgcn_mfma_i32_16x16x64_i8(
                        af[i], bfl[j], acc[i][j], 0, 0, 0);
            }
#pragma unroll
        for (int i = 0; i < 4; ++i) af[i] = afn[i];
    }

    // ---- epilogue: per z-row lane-local top-2 over this wave's 64 cb -----
    // acc[i][j][g]: cb = mw*64 + i*16 + q4*4 + g, z-row = nw*64 + j*16 + cl
    unsigned long long* gs = gstats + (pn * 2 + (unsigned)mw) * 16384u
                                    + pm * 128u + (unsigned)(nw * 64);
#pragma unroll
    for (int jj = 0; jj < 4; ++jj) {
        unsigned m1[8], m2[8];
#pragma unroll
        for (int i = 0; i < 4; ++i)
#pragma unroll
            for (int gp = 0; gp < 2; ++gp) {
                unsigned pa = ((unsigned)acc[i][jj][2 * gp] << 6)
                              + vb + (unsigned)(i * 16 + 2 * gp);
                unsigned pb = ((unsigned)acc[i][jj][2 * gp + 1] << 6)
                              + vb + (unsigned)(i * 16 + 2 * gp + 1);
                m1[i * 2 + gp] = umax_(pa, pb);
                m2[i * 2 + gp] = umin_(pa, pb);
            }
#pragma unroll
        for (int s = 4; s >= 1; s >>= 1)
#pragma unroll
            for (int u = 0; u < 4; ++u) {
                if (u < s) {
                    unsigned a1 = m1[u], a2 = m2[u];
                    unsigned b1 = m1[u + s], b2 = m2[u + s];
                    m1[u] = umax_(a1, b1);
                    m2[u] = umax_(umin_(a1, b1), umax_(a2, b2));
                }
            }
        unsigned t1 = m1[0], t2 = m2[0];
#pragma unroll
        for (int off = 16; off <= 32; off <<= 1) {
            unsigned o1 = (unsigned)__shfl_xor((int)t1, off);
            unsigned o2 = (unsigned)__shfl_xor((int)t2, off);
            t2 = umax_(umax_(t2, o2), umin_(t1, o1));
            t1 = umax_(t1, o1);
        }
        if (q4 == 0)
            gs[jj * 16 + cl] =
                ((unsigned long long)t1 << 32) | (unsigned long long)t2;
    }
}

// ---------------------------------------------------------------------------
// Finalize: rescore + scatter FUSED. 512 blocks x 32 rows = one scatter tile
// (b, j) each; indices never leave LDS. gstats entries kept in registers
// between max-derivation and candidate-gather (no 16MB L2 re-read).
__global__ __launch_bounds__(256) void vq_finalize(
        const float* __restrict__ z, const float* __restrict__ cb,
        const float* __restrict__ z2w,
        const unsigned long long* __restrict__ gstats,
        float* __restrict__ out, float* __restrict__ out_idx) {
    __shared__ float zs[32][32];
    __shared__ unsigned pmax[8][32];
    __shared__ int thrL[32];
    __shared__ unsigned candL[512];    // (r<<13)|k
    __shared__ unsigned blkcnt;
    __shared__ unsigned long long bestL[32];
    __shared__ float tile[32 * 257];   // scatter tile, stride 257 floats

    const int t = threadIdx.x;
    const int bid = blockIdx.x;
    const int n0 = bid * 32;
    const int b = bid >> 5, j = bid & 31;
    const int hw0 = j * 32;
    const int r = t & 31, gc = t >> 5;   // gc in [0,8): 16 groups each

    // phase 1: per-row max of group top1s (= exact global row max); keep e[]
    unsigned long long e[16];
    unsigned m = 0;
#pragma unroll
    for (int g2 = 0; g2 < 16; ++g2) {
        e[g2] = gstats[(size_t)(gc * 16 + g2) * 16384u + (unsigned)(n0 + r)];
        m = umax_(m, (unsigned)(e[g2] >> 32));
    }
    pmax[gc][r] = m;
    if (t == 0) blkcnt = 0;
    __syncthreads();
    if (t < 32) {
        unsigned mm = 0;
#pragma unroll
        for (int g = 0; g < 8; ++g) mm = umax_(mm, pmax[g][t]);
        thrL[t] = (int)(mm >> 6) - MARGIN_INT;   // biased domain both sides
        bestL[t] = ~0ull;
    }
    __syncthreads();

    // phase 2: candidates = group top-1/top-2 entries >= threshold
    {
        int th = thrL[r];
#pragma unroll
        for (int g2 = 0; g2 < 16; ++g2) {
            unsigned p1 = (unsigned)(e[g2] >> 32), p2 = (unsigned)e[g2];
            unsigned kb = (unsigned)(gc * 16 + g2) * 64u;
            if ((int)(p1 >> 6) >= th) {
                unsigned pos = atomicAdd(&blkcnt, 1u);
                if (pos < 512u)
                    candL[pos] = ((unsigned)r << 13) | (kb + (p1 & 63u));
            }
            if ((int)(p2 >> 6) >= th) {
                unsigned pos = atomicAdd(&blkcnt, 1u);
                if (pos < 512u)
                    candL[pos] = ((unsigned)r << 13) | (kb + (p2 & 63u));
            }
        }
    }
    __syncthreads();
    int ns = (int)(blkcnt < 512u ? blkcnt : 512u);

    for (int base = 0; base < ns; base += 256) {
        bool active = base + t < ns;
        int rr0 = 0, k = 0;
        if (active) {
            unsigned v = candL[base + t];
            rr0 = v >> 13; k = v & 8191;
        }
        float sacc = 0.f;
        for (int ch = 0; ch < 8; ++ch) {
            __syncthreads();
            {   // stage 32 channels x 32 rows, coalesced
                int rr = t & 31, cc2 = t >> 5;
#pragma unroll
                for (int u = 0; u < 4; ++u) {
                    int cc = u * 8 + cc2;
                    zs[cc][rr] = z[b * 262144 + (ch * 32 + cc) * 1024 + hw0 + rr];
                }
            }
            __syncthreads();
            if (active) {
                const float4* cbp = (const float4*)(cb + k * 256 + ch * 32);
                float4 A0 = cbp[0], A1 = cbp[1], A2 = cbp[2], A3 = cbp[3];
                float4 A4 = cbp[4], A5 = cbp[5], A6 = cbp[6], A7 = cbp[7];
                float Af[32] = {A0.x,A0.y,A0.z,A0.w, A1.x,A1.y,A1.z,A1.w,
                                A2.x,A2.y,A2.z,A2.w, A3.x,A3.y,A3.z,A3.w,
                                A4.x,A4.y,A4.z,A4.w, A5.x,A5.y,A5.z,A5.w,
                                A6.x,A6.y,A6.z,A6.w, A7.x,A7.y,A7.z,A7.w};
#pragma unroll
                for (int u = 0; u < 32; ++u)
                    sacc = __builtin_fmaf(zs[u][rr0], Af[u], sacc);
            }
        }
        if (active) {
            float d = z2w[n0 + rr0] - 2.0f * sacc;   // single rounding, d > 0
            unsigned long long key =
                ((unsigned long long)__float_as_uint(d) << 32) | (unsigned)k;
            atomicMin(&bestL[rr0], key);
        }
    }
    __syncthreads();
    if (t < 32)
        out_idx[n0 + t] = (float)(unsigned)(bestL[t] & 0xFFFFFFFFu);

    // ---- fused scatter: gather 32 winning cb rows, write out k-coalesced --
    {
        const int c0 = t & 63;
        const int w0 = (t >> 6) * 8;
#pragma unroll
        for (int it = 0; it < 8; ++it) {
            int wr = w0 + it;
            int kk = (int)(unsigned)(bestL[wr] & 0xFFFFFFFFu);
            const float* src = cb + kk * 256 + c0;
            float* drow = tile + wr * 257 + c0;
            drow[0]   = src[0];
            drow[64]  = src[64];
            drow[128] = src[128];
            drow[192] = src[192];
        }
    }
    __syncthreads();

    float* obase = out + b * 262144 + j * 256;
    const int wv = t >> 3, cb8 = (t & 7) * 32;
#pragma unroll
    for (int it = 0; it < 32; ++it)     // it = i; lane = k (coalesced store)
        obase[it * 8192 + t] = tile[wv * 257 + cb8 + it];
}

// ---------------------------------------------------------------------------
// Loss, block = (b, i): z read w-coalesced (staged), out re-read coalesced.
// loss += 1.25/N * sum((zp - zq)^2);  zp(o) = z[b,k,i,j], zq(o) = out[o].
__global__ __launch_bounds__(256) void vq_loss(
        const float* __restrict__ z, const float* __restrict__ out,
        float* __restrict__ loss_out) {
    __shared__ float zs[256][33];
    __shared__ float wsum[4];

    const int t = threadIdx.x;
    const int b = blockIdx.x >> 5, i = blockIdx.x & 31;

#pragma unroll
    for (int it = 0; it < 32; ++it) {
        int k = it * 8 + (t >> 5);
        zs[k][t & 31] = z[b * 262144 + k * 1024 + i * 32 + (t & 31)];
    }
    __syncthreads();

    const float* ob = out + b * 262144 + i * 8192;
    float lsum = 0.f;
#pragma unroll 4
    for (int it = 0; it < 32; ++it) {   // it = j; lane = k
        float d = zs[t][it] - ob[it * 256 + t];
        lsum = __builtin_fmaf(d, d, lsum);
    }
#pragma unroll
    for (int off = 32; off >= 1; off >>= 1) lsum += __shfl_down(lsum, off, 64);
    int lane = t & 63, wv = t >> 6;
    if (lane == 0) wsum[wv] = lsum;
    __syncthreads();
    if (t == 0)
        atomicAdd(loss_out, (wsum[0] + wsum[1] + wsum[2] + wsum[3]) *
                            (1.25f / (float)NELEM));
}

// ---------------------------------------------------------------------------
extern "C" void kernel_launch(void* const* d_in, const int* in_sizes, int n_in,
                              void* d_out, int out_size, void* d_ws, size_t ws_size,
                              hipStream_t stream) {
    const float* z  = (const float*)d_in[0];
    const float* cb = (const float*)d_in[1];
    float* out = (float*)d_out;

    char* ws = (char*)d_ws;
    char* zbi8               = ws;                                   // 4 MB
    char* cbbi8              = ws + 4194304;                         // 2 MB
    unsigned long long* gstats = (unsigned long long*)(ws + 6291456); // 16 MB
    float* z2w               = (float*)(ws + 23068672);

    vq_prep<<<320, 128, 0, stream>>>(z, cb, z2w, zbi8, cbbi8, out + NELEM);

    vq_gemm<<<8192, 256, 0, stream>>>(zbi8, cbbi8, gstats);

    vq_finalize<<<512, 256, 0, stream>>>(z, cb, z2w, gstats,
                                         out, out + NELEM + 1);

    vq_loss<<<512, 256, 0, stream>>>(z, out, out + NELEM);
}

// Round 4
// 147.341 us; speedup vs baseline: 1.6897x; 1.0387x over previous
//
#include <hip/hip_runtime.h>
#include <stdint.h>

// Problem constants
#define NROWS 16384   // B*H*W = 16*32*32
#define KENT  8192    // codebook entries
#define CDIM  256     // embedding dim
#define NELEM 4194304 // B*H*W*C elements of z / z_q

// int8 screen scales: z*22 (clamp +-127 = 5.77 sigma), cb*127*8192 (<=0.5 LSB)
#define ZSCALE 22.0f
#define ESCALE 1040384.0f      // 127*8192, exact in fp32
#define MARGIN_INT 4096        // = 1.79e-4 real ~ 8 sigma of i8-quant error
#define SBIAS 4194304          // 1<<22, |score| <= 256*127*127 = 4129024 < SBIAS

// ws layout (bytes):
//   [0,        4194304): zbi8   i8[4M]   z int8, k-major tile layout
//   [4194304,  6291456): cbi8   i8[2M]   codebook int8, same layout
//   [6291456, 23068672): gstats u64[128][16384]  per (64-entry cb group, row):
//                        (top1 << 32) | top2, packed (score+SBIAS)<<6 | col6
//   [23068672,23134208): z2w   float[16384]  np-tree row norms

typedef int v4i __attribute__((ext_vector_type(4)));

__device__ inline int q8(float x, float s) {
    int v = __float2int_rn(x * s);
    return v < -127 ? -127 : (v > 127 ? 127 : v);
}
__device__ inline unsigned pk4(int a, int b, int c, int d) {
    return (a & 255) | ((b & 255) << 8) | ((c & 255) << 16) | ((d & 255) << 24);
}
__device__ inline unsigned umax_(unsigned a, unsigned b) { return a > b ? a : b; }
__device__ inline unsigned umin_(unsigned a, unsigned b) { return a < b ? a : b; }
__device__ inline void gload_lds16(const void* g, void* l) {
    __builtin_amdgcn_global_load_lds(
        (const __attribute__((address_space(1))) void*)g,
        (__attribute__((address_space(3))) void*)l, 16, 0, 0);
}

// ---------------------------------------------------------------------------
// Fused prep v2 -- 3x parallelism of v1 (1536 waves vs 640; v1 was
// latency-bound at 0.6 waves/SIMD). Same VALIDATED arithmetic:
//  blocks 0..255  = prep_z: 64 rows/block, 4 threads/row split by
//                   (c-half blk, j-half jh); each computes the exact same
//                   np sub-tree; combined via LDS in the original order
//                   C = p0123 + p4567, z2 = bs_blk0 + bs_blk1 (bit-exact).
//  blocks 256..383 = prep_cb: half-panel per block, 4 threads/row.
__global__ __launch_bounds__(256) void vq_prep(
        const float* __restrict__ z, const float* __restrict__ cb,
        float* __restrict__ z2w, char* __restrict__ zbi8,
        char* __restrict__ cbbi8, float* __restrict__ loss_out) {
    const int t = threadIdx.x;
    const int bid = blockIdx.x;

    if (bid >= 256) {   // ---- prep_cb: half-panel (64 rows), 4 thr/row
        const int ppi = bid - 256;            // [0,128)
        const int p = ppi >> 1, h = ppi & 1;  // panel, row-half
        const int r = t & 63, qh = t >> 6;    // row-in-half, q-quarter
        const int row = h * 64 + r;           // row in panel [0,128)
        char* dst = cbbi8 + p * 32768;
        const float* src = cb + (p * 128 + row) * 256;
#pragma unroll
        for (int qq = 0; qq < 4; ++qq) {
            const int q = qh * 4 + qq;
            float4 a = *(const float4*)(src + q * 16);
            float4 b = *(const float4*)(src + q * 16 + 4);
            float4 c = *(const float4*)(src + q * 16 + 8);
            float4 d = *(const float4*)(src + q * 16 + 12);
            uint4 v;
            v.x = pk4(q8(a.x,ESCALE), q8(a.y,ESCALE), q8(a.z,ESCALE), q8(a.w,ESCALE));
            v.y = pk4(q8(b.x,ESCALE), q8(b.y,ESCALE), q8(b.z,ESCALE), q8(b.w,ESCALE));
            v.z = pk4(q8(c.x,ESCALE), q8(c.y,ESCALE), q8(c.z,ESCALE), q8(c.w,ESCALE));
            v.w = pk4(q8(d.x,ESCALE), q8(d.y,ESCALE), q8(d.z,ESCALE), q8(d.w,ESCALE));
            *(uint4*)&dst[(q * 128 + row) * 16] = v;
        }
        if (ppi == 0 && t == 0) loss_out[0] = 0.f;
        return;
    }

    // ---- prep_z: 64 rows/block; part = wave: (blk = c-half, jh = j-half)
    __shared__ float pprt[2][64][17];   // jh=1 partials (p4567), padded
    __shared__ float s64[64];
    const int r = t & 63;
    const int part = t >> 6;            // wave index
    const int blk = part >> 1, jh = part & 1;
    const int n = bid * 64 + r;
    const int b = n >> 10, hw = n & 1023;
    const float* base = z + b * 262144 + hw;

    const int p = n >> 7, rp = n & 127;
    char* dst = zbi8 + p * 32768;

    float t0[16], p01[16], pr[16];

#pragma unroll
    for (int jj = 0; jj < 4; ++jj) {
        const int j = jh * 4 + jj;
        float a[16];
#pragma unroll
        for (int L = 0; L < 16; ++L)
            a[L] = base[(blk * 128 + L + 16 * j) * 1024];
        int qb[16];
#pragma unroll
        for (int L = 0; L < 16; ++L) {
            qb[L] = q8(a[L], ZSCALE);
            float sq = a[L] * a[L];
            asm volatile("" : "+v"(sq));   // forbid FMA contraction into adds
            // half-tree: pr = (sq0+sq1) + (sq2+sq3)   (exact v1 association)
            if (jj == 0)      t0[L] = sq;
            else if (jj == 1) p01[L] = t0[L] + sq;
            else if (jj == 2) t0[L] = sq;
            else              pr[L] = p01[L] + (t0[L] + sq);
        }
        uint4 v;
        v.x = pk4(qb[0], qb[1], qb[2], qb[3]);
        v.y = pk4(qb[4], qb[5], qb[6], qb[7]);
        v.z = pk4(qb[8], qb[9], qb[10], qb[11]);
        v.w = pk4(qb[12], qb[13], qb[14], qb[15]);
        *(uint4*)&dst[((blk * 8 + j) * 128 + rp) * 16] = v;
    }

    if (jh == 1) {   // publish p4567 partials
#pragma unroll
        for (int L = 0; L < 16; ++L) pprt[blk][r][L] = pr[L];
    }
    __syncthreads();
    float bs = 0.f;
    if (jh == 0) {   // combine in the validated order: C = p0123 + p4567
        float C[16];
#pragma unroll
        for (int L = 0; L < 16; ++L) C[L] = pr[L] + pprt[blk][r][L];
        float t8[8];
#pragma unroll
        for (int L = 0; L < 8; ++L) t8[L] = C[L] + C[L + 8];
        float t4[4];
#pragma unroll
        for (int L = 0; L < 4; ++L) t4[L] = t8[L] + t8[L + 4];
        float t2a = t4[0] + t4[2];
        float t2b = t4[1] + t4[3];
        bs = t2a + t2b;
        if (blk == 1) s64[r] = bs;
    }
    __syncthreads();
    if (part == 0) z2w[n] = bs + s64[r];   // bs(blk0) + bs(blk1), v1 order
}

// ---------------------------------------------------------------------------
// int8 MFMA screen v8 + setprio: one-panel structure (grid 8192, whole z
// panel in LDS, ONE staging drain, 1-deep cb prefetch from L2), swapped
// operands mfma(cb, z) so each z-row's 64 scores are lane-local; top-2 =
// register tree + 2 shfl. Fits the 128-reg unified cap of (256,4): 64 AGPR
// + 64 VGPR (round-2's 4-panel variant spilled -> 560 MB scratch; do NOT
// widen). s_setprio(1) wraps the MFMA cluster (phase-diverse blocks).
__global__ __launch_bounds__(256, 4) void vq_gemm(
        const char* __restrict__ zbi8,
        const char* __restrict__ cbbi8,
        unsigned long long* __restrict__ gstats) {
    __shared__ __align__(16) char smem[32768];   // z panel

    const int tid = threadIdx.x;
    const int w = tid >> 6, l = tid & 63;
    const int q4 = l >> 4, cl = l & 15;
    const int mw = w & 1, nw = w >> 1;   // mw: cb 64-half, nw: z 64-half

    // XCD-locality swizzle (validated r5): 16 pm x phased 16 pn per XCD
    const unsigned bx = blockIdx.x;
    const unsigned xcd = bx & 7, local = bx >> 3;
    const unsigned png = local >> 8;
    const unsigned rem = local & 255;
    const unsigned pm = (rem >> 4) * 8 + xcd;
    const unsigned pn = png * 16 + (rem & 15);

    const char* Ab = zbi8 + pm * 32768;
    const char* Bb = cbbi8 + pn * 32768;

    // stage whole z panel: 8 issues x 256 thr x 16B = 32KB
#pragma unroll
    for (int u = 0; u < 8; ++u)
        gload_lds16(Ab + u * 4096 + tid * 16, smem + u * 4096 + (w << 10));

    // cb fragments (MFMA A operand) streamed from L2: row = mw*64+i*16+cl,
    // kchunk = kt*4+q4; i via +256, kt via +8192
    const char* abase = Bb + (q4 * 128 + mw * 64 + cl) * 16;
    v4i af[4], afn[4];
#pragma unroll
    for (int i = 0; i < 4; ++i)
        af[i] = *(const v4i*)(abase + i * 256);

    const unsigned vb = ((unsigned)SBIAS << 6) + (unsigned)(q4 * 4);

    v4i acc[4][4];
    __syncthreads();   // single staging drain (af prologue rides along)

#pragma unroll
    for (int kt = 0; kt < 4; ++kt) {
        v4i bfl[4];
#pragma unroll
        for (int j = 0; j < 4; ++j)
            bfl[j] = *(const v4i*)(smem + kt * 8192 + q4 * 2048
                                        + nw * 1024 + j * 256 + cl * 16);
        if (kt < 3) {
#pragma unroll
            for (int i = 0; i < 4; ++i)
                afn[i] = *(const v4i*)(abase + (kt + 1) * 8192 + i * 256);
        }
        __builtin_amdgcn_s_setprio(1);
#pragma unroll
        for (int i = 0; i < 4; ++i)
#pragma unroll
            for (int j = 0; j < 4; ++j) {
                if (kt == 0)
                    acc[i][j] = __builtin_amdgcn_mfma_i32_16x16x64_i8(
                        af[i], bfl[j], (v4i)0, 0, 0, 0);
                else
                    acc[i][j] = __builtin_amdgcn_mfma_i32_16x16x64_i8(
                        af[i], bfl[j], acc[i][j], 0, 0, 0);
            }
        __builtin_amdgcn_s_setprio(0);
#pragma unroll
        for (int i = 0; i < 4; ++i) af[i] = afn[i];
    }

    // ---- epilogue: per z-row lane-local top-2 over this wave's 64 cb -----
    // acc[i][j][g]: cb = mw*64 + i*16 + q4*4 + g, z-row = nw*64 + j*16 + cl
    unsigned long long* gs = gstats + (pn * 2 + (unsigned)mw) * 16384u
                                    + pm * 128u + (unsigned)(nw * 64);
#pragma unroll
    for (int jj = 0; jj < 4; ++jj) {
        unsigned m1[8], m2[8];
#pragma unroll
        for (int i = 0; i < 4; ++i)
#pragma unroll
            for (int gp = 0; gp < 2; ++gp) {
                unsigned pa = ((unsigned)acc[i][jj][2 * gp] << 6)
                              + vb + (unsigned)(i * 16 + 2 * gp);
                unsigned pb = ((unsigned)acc[i][jj][2 * gp + 1] << 6)
                              + vb + (unsigned)(i * 16 + 2 * gp + 1);
                m1[i * 2 + gp] = umax_(pa, pb);
                m2[i * 2 + gp] = umin_(pa, pb);
            }
#pragma unroll
        for (int s = 4; s >= 1; s >>= 1)
#pragma unroll
            for (int u = 0; u < 4; ++u) {
                if (u < s) {
                    unsigned a1 = m1[u], a2 = m2[u];
                    unsigned b1 = m1[u + s], b2 = m2[u + s];
                    m1[u] = umax_(a1, b1);
                    m2[u] = umax_(umin_(a1, b1), umax_(a2, b2));
                }
            }
        unsigned t1 = m1[0], t2 = m2[0];
#pragma unroll
        for (int off = 16; off <= 32; off <<= 1) {
            unsigned o1 = (unsigned)__shfl_xor((int)t1, off);
            unsigned o2 = (unsigned)__shfl_xor((int)t2, off);
            t2 = umax_(umax_(t2, o2), umin_(t1, o1));
            t1 = umax_(t1, o1);
        }
        if (q4 == 0)
            gs[jj * 16 + cl] =
                ((unsigned long long)t1 << 32) | (unsigned long long)t2;
    }
}

// ---------------------------------------------------------------------------
// Finalize: rescore + scatter FUSED. 512 blocks x 32 rows = one scatter tile
// (b, j) each; indices never leave LDS. gstats entries kept in registers
// between max-derivation and candidate-gather (no 16MB L2 re-read).
__global__ __launch_bounds__(256) void vq_finalize(
        const float* __restrict__ z, const float* __restrict__ cb,
        const float* __restrict__ z2w,
        const unsigned long long* __restrict__ gstats,
        float* __restrict__ out, float* __restrict__ out_idx) {
    __shared__ float zs[32][32];
    __shared__ unsigned pmax[8][32];
    __shared__ int thrL[32];
    __shared__ unsigned candL[512];    // (r<<13)|k
    __shared__ unsigned blkcnt;
    __shared__ unsigned long long bestL[32];
    __shared__ float tile[32 * 257];   // scatter tile, stride 257 floats

    const int t = threadIdx.x;
    const int bid = blockIdx.x;
    const int n0 = bid * 32;
    const int b = bid >> 5, j = bid & 31;
    const int hw0 = j * 32;
    const int r = t & 31, gc = t >> 5;   // gc in [0,8): 16 groups each

    // phase 1: per-row max of group top1s (= exact global row max); keep e[]
    unsigned long long e[16];
    unsigned m = 0;
#pragma unroll
    for (int g2 = 0; g2 < 16; ++g2) {
        e[g2] = gstats[(size_t)(gc * 16 + g2) * 16384u + (unsigned)(n0 + r)];
        m = umax_(m, (unsigned)(e[g2] >> 32));
    }
    pmax[gc][r] = m;
    if (t == 0) blkcnt = 0;
    __syncthreads();
    if (t < 32) {
        unsigned mm = 0;
#pragma unroll
        for (int g = 0; g < 8; ++g) mm = umax_(mm, pmax[g][t]);
        thrL[t] = (int)(mm >> 6) - MARGIN_INT;   // biased domain both sides
        bestL[t] = ~0ull;
    }
    __syncthreads();

    // phase 2: candidates = group top-1/top-2 entries >= threshold
    {
        int th = thrL[r];
#pragma unroll
        for (int g2 = 0; g2 < 16; ++g2) {
            unsigned p1 = (unsigned)(e[g2] >> 32), p2 = (unsigned)e[g2];
            unsigned kb = (unsigned)(gc * 16 + g2) * 64u;
            if ((int)(p1 >> 6) >= th) {
                unsigned pos = atomicAdd(&blkcnt, 1u);
                if (pos < 512u)
                    candL[pos] = ((unsigned)r << 13) | (kb + (p1 & 63u));
            }
            if ((int)(p2 >> 6) >= th) {
                unsigned pos = atomicAdd(&blkcnt, 1u);
                if (pos < 512u)
                    candL[pos] = ((unsigned)r << 13) | (kb + (p2 & 63u));
            }
        }
    }
    __syncthreads();
    int ns = (int)(blkcnt < 512u ? blkcnt : 512u);

    for (int base = 0; base < ns; base += 256) {
        bool active = base + t < ns;
        int rr0 = 0, k = 0;
        if (active) {
            unsigned v = candL[base + t];
            rr0 = v >> 13; k = v & 8191;
        }
        float sacc = 0.f;
        for (int ch = 0; ch < 8; ++ch) {
            __syncthreads();
            {   // stage 32 channels x 32 rows, coalesced
                int rr = t & 31, cc2 = t >> 5;
#pragma unroll
                for (int u = 0; u < 4; ++u) {
                    int cc = u * 8 + cc2;
                    zs[cc][rr] = z[b * 262144 + (ch * 32 + cc) * 1024 + hw0 + rr];
                }
            }
            __syncthreads();
            if (active) {
                const float4* cbp = (const float4*)(cb + k * 256 + ch * 32);
                float4 A0 = cbp[0], A1 = cbp[1], A2 = cbp[2], A3 = cbp[3];
                float4 A4 = cbp[4], A5 = cbp[5], A6 = cbp[6], A7 = cbp[7];
                float Af[32] = {A0.x,A0.y,A0.z,A0.w, A1.x,A1.y,A1.z,A1.w,
                                A2.x,A2.y,A2.z,A2.w, A3.x,A3.y,A3.z,A3.w,
                                A4.x,A4.y,A4.z,A4.w, A5.x,A5.y,A5.z,A5.w,
                                A6.x,A6.y,A6.z,A6.w, A7.x,A7.y,A7.z,A7.w};
#pragma unroll
                for (int u = 0; u < 32; ++u)
                    sacc = __builtin_fmaf(zs[u][rr0], Af[u], sacc);
            }
        }
        if (active) {
            float d = z2w[n0 + rr0] - 2.0f * sacc;   // single rounding, d > 0
            unsigned long long key =
                ((unsigned long long)__float_as_uint(d) << 32) | (unsigned)k;
            atomicMin(&bestL[rr0], key);
        }
    }
    __syncthreads();
    if (t < 32)
        out_idx[n0 + t] = (float)(unsigned)(bestL[t] & 0xFFFFFFFFu);

    // ---- fused scatter: gather 32 winning cb rows, write out k-coalesced --
    {
        const int c0 = t & 63;
        const int w0 = (t >> 6) * 8;
#pragma unroll
        for (int it = 0; it < 8; ++it) {
            int wr = w0 + it;
            int kk = (int)(unsigned)(bestL[wr] & 0xFFFFFFFFu);
            const float* src = cb + kk * 256 + c0;
            float* drow = tile + wr * 257 + c0;
            drow[0]   = src[0];
            drow[64]  = src[64];
            drow[128] = src[128];
            drow[192] = src[192];
        }
    }
    __syncthreads();

    float* obase = out + b * 262144 + j * 256;
    const int wv = t >> 3, cb8 = (t & 7) * 32;
#pragma unroll
    for (int it = 0; it < 32; ++it)     // it = i; lane = k (coalesced store)
        obase[it * 8192 + t] = tile[wv * 257 + cb8 + it];
}

// ---------------------------------------------------------------------------
// Loss, block = (b, i): z read w-coalesced (staged), out re-read coalesced.
// loss += 1.25/N * sum((zp - zq)^2);  zp(o) = z[b,k,i,j], zq(o) = out[o].
__global__ __launch_bounds__(256) void vq_loss(
        const float* __restrict__ z, const float* __restrict__ out,
        float* __restrict__ loss_out) {
    __shared__ float zs[256][33];
    __shared__ float wsum[4];

    const int t = threadIdx.x;
    const int b = blockIdx.x >> 5, i = blockIdx.x & 31;

#pragma unroll
    for (int it = 0; it < 32; ++it) {
        int k = it * 8 + (t >> 5);
        zs[k][t & 31] = z[b * 262144 + k * 1024 + i * 32 + (t & 31)];
    }
    __syncthreads();

    const float* ob = out + b * 262144 + i * 8192;
    float lsum = 0.f;
#pragma unroll 4
    for (int it = 0; it < 32; ++it) {   // it = j; lane = k
        float d = zs[t][it] - ob[it * 256 + t];
        lsum = __builtin_fmaf(d, d, lsum);
    }
#pragma unroll
    for (int off = 32; off >= 1; off >>= 1) lsum += __shfl_down(lsum, off, 64);
    int lane = t & 63, wv = t >> 6;
    if (lane == 0) wsum[wv] = lsum;
    __syncthreads();
    if (t == 0)
        atomicAdd(loss_out, (wsum[0] + wsum[1] + wsum[2] + wsum[3]) *
                            (1.25f / (float)NELEM));
}

// ---------------------------------------------------------------------------
extern "C" void kernel_launch(void* const* d_in, const int* in_sizes, int n_in,
                              void* d_out, int out_size, void* d_ws, size_t ws_size,
                              hipStream_t stream) {
    const float* z  = (const float*)d_in[0];
    const float* cb = (const float*)d_in[1];
    float* out = (float*)d_out;

    char* ws = (char*)d_ws;
    char* zbi8               = ws;                                   // 4 MB
    char* cbbi8              = ws + 4194304;                         // 2 MB
    unsigned long long* gstats = (unsigned long long*)(ws + 6291456); // 16 MB
    float* z2w               = (float*)(ws + 23068672);

    vq_prep<<<384, 256, 0, stream>>>(z, cb, z2w, zbi8, cbbi8, out + NELEM);

    vq_gemm<<<8192, 256, 0, stream>>>(zbi8, cbbi8, gstats);

    vq_finalize<<<512, 256, 0, stream>>>(z, cb, z2w, gstats,
                                         out, out + NELEM + 1);

    vq_loss<<<512, 256, 0, stream>>>(z, out, out + NELEM);
}

// Round 6
// 143.806 us; speedup vs baseline: 1.7312x; 1.0246x over previous
//
#include <hip/hip_runtime.h>
#include <stdint.h>

// Problem constants
#define NROWS 16384   // B*H*W = 16*32*32
#define KENT  8192    // codebook entries
#define CDIM  256     // embedding dim
#define NELEM 4194304 // B*H*W*C elements of z / z_q

// int8 screen scales: z*22 (clamp +-127 = 5.77 sigma), cb*127*8192 (<=0.5 LSB)
#define ZSCALE 22.0f
#define ESCALE 1040384.0f      // 127*8192, exact in fp32
#define MARGIN_INT 4096        // = 1.79e-4 real ~ 8 sigma of i8-quant error
#define SBIAS 4194304          // 1<<22, |score| <= 256*127*127 = 4129024 < SBIAS

// ws layout (bytes):
//   [0,        4194304): zbi8   i8[4M]   z int8, k-major tile layout
//   [4194304,  6291456): cbi8   i8[2M]   codebook int8, same layout
//   [6291456, 23068672): gstats u64[128][16384]  per (64-entry cb group, row):
//                        (top1 << 32) | top2, packed (score+SBIAS)<<6 | col6
//   [23068672,23134208): z2w   float[16384]  np-tree row norms

typedef int v4i __attribute__((ext_vector_type(4)));

__device__ inline int q8(float x, float s) {
    int v = __float2int_rn(x * s);
    return v < -127 ? -127 : (v > 127 ? 127 : v);
}
__device__ inline unsigned pk4(int a, int b, int c, int d) {
    return (a & 255) | ((b & 255) << 8) | ((c & 255) << 16) | ((d & 255) << 24);
}
__device__ inline unsigned umax_(unsigned a, unsigned b) { return a > b ? a : b; }
__device__ inline unsigned umin_(unsigned a, unsigned b) { return a < b ? a : b; }
__device__ inline void gload_lds16(const void* g, void* l) {
    __builtin_amdgcn_global_load_lds(
        (const __attribute__((address_space(1))) void*)g,
        (__attribute__((address_space(3))) void*)l, 16, 0, 0);
}

// ---------------------------------------------------------------------------
// Fused prep v2 (VALIDATED r4): blocks 0..255 = prep_z (np-tree z2 + i8 tile,
// 4 thr/row), blocks 256..383 = prep_cb (half-panel, 4 thr/row), loss init.
__global__ __launch_bounds__(256) void vq_prep(
        const float* __restrict__ z, const float* __restrict__ cb,
        float* __restrict__ z2w, char* __restrict__ zbi8,
        char* __restrict__ cbbi8, float* __restrict__ loss_out) {
    const int t = threadIdx.x;
    const int bid = blockIdx.x;

    if (bid >= 256) {   // ---- prep_cb: half-panel (64 rows), 4 thr/row
        const int ppi = bid - 256;            // [0,128)
        const int p = ppi >> 1, h = ppi & 1;  // panel, row-half
        const int r = t & 63, qh = t >> 6;    // row-in-half, q-quarter
        const int row = h * 64 + r;           // row in panel [0,128)
        char* dst = cbbi8 + p * 32768;
        const float* src = cb + (p * 128 + row) * 256;
#pragma unroll
        for (int qq = 0; qq < 4; ++qq) {
            const int q = qh * 4 + qq;
            float4 a = *(const float4*)(src + q * 16);
            float4 b = *(const float4*)(src + q * 16 + 4);
            float4 c = *(const float4*)(src + q * 16 + 8);
            float4 d = *(const float4*)(src + q * 16 + 12);
            uint4 v;
            v.x = pk4(q8(a.x,ESCALE), q8(a.y,ESCALE), q8(a.z,ESCALE), q8(a.w,ESCALE));
            v.y = pk4(q8(b.x,ESCALE), q8(b.y,ESCALE), q8(b.z,ESCALE), q8(b.w,ESCALE));
            v.z = pk4(q8(c.x,ESCALE), q8(c.y,ESCALE), q8(c.z,ESCALE), q8(c.w,ESCALE));
            v.w = pk4(q8(d.x,ESCALE), q8(d.y,ESCALE), q8(d.z,ESCALE), q8(d.w,ESCALE));
            *(uint4*)&dst[(q * 128 + row) * 16] = v;
        }
        if (ppi == 0 && t == 0) loss_out[0] = 0.f;
        return;
    }

    // ---- prep_z: 64 rows/block; part = wave: (blk = c-half, jh = j-half)
    __shared__ float pprt[2][64][17];   // jh=1 partials (p4567), padded
    __shared__ float s64[64];
    const int r = t & 63;
    const int part = t >> 6;            // wave index
    const int blk = part >> 1, jh = part & 1;
    const int n = bid * 64 + r;
    const int b = n >> 10, hw = n & 1023;
    const float* base = z + b * 262144 + hw;

    const int p = n >> 7, rp = n & 127;
    char* dst = zbi8 + p * 32768;

    float t0[16], p01[16], pr[16];

#pragma unroll
    for (int jj = 0; jj < 4; ++jj) {
        const int j = jh * 4 + jj;
        float a[16];
#pragma unroll
        for (int L = 0; L < 16; ++L)
            a[L] = base[(blk * 128 + L + 16 * j) * 1024];
        int qb[16];
#pragma unroll
        for (int L = 0; L < 16; ++L) {
            qb[L] = q8(a[L], ZSCALE);
            float sq = a[L] * a[L];
            asm volatile("" : "+v"(sq));   // forbid FMA contraction into adds
            // half-tree: pr = (sq0+sq1) + (sq2+sq3)   (exact v1 association)
            if (jj == 0)      t0[L] = sq;
            else if (jj == 1) p01[L] = t0[L] + sq;
            else if (jj == 2) t0[L] = sq;
            else              pr[L] = p01[L] + (t0[L] + sq);
        }
        uint4 v;
        v.x = pk4(qb[0], qb[1], qb[2], qb[3]);
        v.y = pk4(qb[4], qb[5], qb[6], qb[7]);
        v.z = pk4(qb[8], qb[9], qb[10], qb[11]);
        v.w = pk4(qb[12], qb[13], qb[14], qb[15]);
        *(uint4*)&dst[((blk * 8 + j) * 128 + rp) * 16] = v;
    }

    if (jh == 1) {   // publish p4567 partials
#pragma unroll
        for (int L = 0; L < 16; ++L) pprt[blk][r][L] = pr[L];
    }
    __syncthreads();
    float bs = 0.f;
    if (jh == 0) {   // combine in the validated order: C = p0123 + p4567
        float C[16];
#pragma unroll
        for (int L = 0; L < 16; ++L) C[L] = pr[L] + pprt[blk][r][L];
        float t8[8];
#pragma unroll
        for (int L = 0; L < 8; ++L) t8[L] = C[L] + C[L + 8];
        float t4[4];
#pragma unroll
        for (int L = 0; L < 4; ++L) t4[L] = t8[L] + t8[L + 4];
        float t2a = t4[0] + t4[2];
        float t2b = t4[1] + t4[3];
        bs = t2a + t2b;
        if (blk == 1) s64[r] = bs;
    }
    __syncthreads();
    if (part == 0) z2w[n] = bs + s64[r];   // bs(blk0) + bs(blk1), v1 order
}

// ---------------------------------------------------------------------------
// int8 MFMA screen v9: PERSISTENT blocks. Grid 1024 (= exactly 4 blocks/CU);
// each block: 2 A-panels (ph) x 4 pn tiles per panel. Staging + vmcnt(0)
// drain paid 2x instead of 8x per CU slot; tiles sharing a panel read LDS
// read-only (no barrier between pn iterations). Per-tile code is VALIDATED
// r4 v8: swapped operands mfma(cb, z), lane-local top-2, register tree + 2
// shfl. #pragma unroll 1 on outer loops so acc never coexists across tiles
// (round-2 spill lesson: 128-reg unified cap at (256,4)).
// Coverage: ph=0 -> pm in [0,64), ph=1 -> pm in [64,128); pn = png*16 +
// (local0 & 15), png in [0,4). Each (pm,pn) tile exactly once.
__global__ __launch_bounds__(256, 4) void vq_gemm(
        const char* __restrict__ zbi8,
        const char* __restrict__ cbbi8,
        unsigned long long* __restrict__ gstats) {
    __shared__ __align__(16) char smem[32768];   // z panel

    const int tid = threadIdx.x;
    const int w = tid >> 6, l = tid & 63;
    const int q4 = l >> 4, cl = l & 15;
    const int mw = w & 1, nw = w >> 1;   // mw: cb 64-half, nw: z 64-half

    const unsigned xcd = (unsigned)blockIdx.x & 7u;
    const unsigned local0 = (unsigned)blockIdx.x >> 3;   // [0,128)
    const unsigned vb = ((unsigned)SBIAS << 6) + (unsigned)(q4 * 4);

#pragma unroll 1
    for (int ph = 0; ph < 2; ++ph) {
        const unsigned rem = (local0 + (unsigned)ph * 128u) & 255u;
        const unsigned pm = (rem >> 4) * 8u + xcd;
        const char* Ab = zbi8 + pm * 32768u;

        __syncthreads();   // all waves done reading previous panel
#pragma unroll
        for (int u = 0; u < 8; ++u)
            gload_lds16(Ab + u * 4096 + tid * 16, smem + u * 4096 + (w << 10));

#pragma unroll 1
        for (int png = 0; png < 4; ++png) {
            const unsigned pn = (unsigned)png * 16u + (rem & 15u);
            const char* abase = cbbi8 + pn * 32768u
                              + (q4 * 128 + mw * 64 + cl) * 16;
            v4i af[4], afn[4];
#pragma unroll
            for (int i = 0; i < 4; ++i)
                af[i] = *(const v4i*)(abase + i * 256);

            v4i acc[4][4];
            if (png == 0) __syncthreads();   // single staging drain per panel

#pragma unroll
            for (int kt = 0; kt < 4; ++kt) {
                v4i bfl[4];
#pragma unroll
                for (int j = 0; j < 4; ++j)
                    bfl[j] = *(const v4i*)(smem + kt * 8192 + q4 * 2048
                                           + nw * 1024 + j * 256 + cl * 16);
                if (kt < 3) {
#pragma unroll
                    for (int i = 0; i < 4; ++i)
                        afn[i] = *(const v4i*)(abase + (kt + 1) * 8192 + i * 256);
                }
                __builtin_amdgcn_s_setprio(1);
#pragma unroll
                for (int i = 0; i < 4; ++i)
#pragma unroll
                    for (int j = 0; j < 4; ++j) {
                        if (kt == 0)
                            acc[i][j] = __builtin_amdgcn_mfma_i32_16x16x64_i8(
                                af[i], bfl[j], (v4i)0, 0, 0, 0);
                        else
                            acc[i][j] = __builtin_amdgcn_mfma_i32_16x16x64_i8(
                                af[i], bfl[j], acc[i][j], 0, 0, 0);
                    }
                __builtin_amdgcn_s_setprio(0);
#pragma unroll
                for (int i = 0; i < 4; ++i) af[i] = afn[i];
            }

            // epilogue: per z-row lane-local top-2 over this wave's 64 cb
            // acc[i][j][g]: cb = mw*64+i*16+q4*4+g, z-row = nw*64+j*16+cl
            unsigned long long* gs = gstats
                + (pn * 2 + (unsigned)mw) * 16384u
                + pm * 128u + (unsigned)(nw * 64);
#pragma unroll
            for (int jj = 0; jj < 4; ++jj) {
                unsigned m1[8], m2[8];
#pragma unroll
                for (int i = 0; i < 4; ++i)
#pragma unroll
                    for (int gp = 0; gp < 2; ++gp) {
                        unsigned pa = ((unsigned)acc[i][jj][2 * gp] << 6)
                                      + vb + (unsigned)(i * 16 + 2 * gp);
                        unsigned pb = ((unsigned)acc[i][jj][2 * gp + 1] << 6)
                                      + vb + (unsigned)(i * 16 + 2 * gp + 1);
                        m1[i * 2 + gp] = umax_(pa, pb);
                        m2[i * 2 + gp] = umin_(pa, pb);
                    }
#pragma unroll
                for (int s = 4; s >= 1; s >>= 1)
#pragma unroll
                    for (int u = 0; u < 4; ++u) {
                        if (u < s) {
                            unsigned a1 = m1[u], a2 = m2[u];
                            unsigned b1 = m1[u + s], b2 = m2[u + s];
                            m1[u] = umax_(a1, b1);
                            m2[u] = umax_(umin_(a1, b1), umax_(a2, b2));
                        }
                    }
                unsigned t1 = m1[0], t2 = m2[0];
#pragma unroll
                for (int off = 16; off <= 32; off <<= 1) {
                    unsigned o1 = (unsigned)__shfl_xor((int)t1, off);
                    unsigned o2 = (unsigned)__shfl_xor((int)t2, off);
                    t2 = umax_(umax_(t2, o2), umin_(t1, o1));
                    t1 = umax_(t1, o1);
                }
                if (q4 == 0)
                    gs[jj * 16 + cl] =
                        ((unsigned long long)t1 << 32) | (unsigned long long)t2;
            }
        }
    }
}

// ---------------------------------------------------------------------------
// Finalize v3: rescore + scatter fused (VALIDATED r4 logic), z tile staged
// ONCE as zs[256][32] (was 8 stagings + 16 barriers per candidate batch).
// Same FMA accumulation order (ch-major, u-minor) -- bit-exact vs r4.
// LDS ~69 KB -> 2 blocks/CU; grid 512 = exactly resident.
__global__ __launch_bounds__(256) void vq_finalize(
        const float* __restrict__ z, const float* __restrict__ cb,
        const float* __restrict__ z2w,
        const unsigned long long* __restrict__ gstats,
        float* __restrict__ out, float* __restrict__ out_idx) {
    __shared__ float zs[256][32];      // [c][r], 32 KB
    __shared__ unsigned pmax[8][32];
    __shared__ int thrL[32];
    __shared__ unsigned candL[512];    // (r<<13)|k
    __shared__ unsigned blkcnt;
    __shared__ unsigned long long bestL[32];
    __shared__ float tile[32 * 257];   // scatter tile, stride 257 floats

    const int t = threadIdx.x;
    const int bid = blockIdx.x;
    const int n0 = bid * 32;
    const int b = bid >> 5, j = bid & 31;
    const int hw0 = j * 32;
    const int r = t & 31, gc = t >> 5;   // gc in [0,8): 16 groups each

    // stage z once: 256 channels x 32 rows, coalesced (128B per 32 lanes)
    {
        const int rr = t & 31, cc2 = t >> 5;
#pragma unroll
        for (int u = 0; u < 32; ++u) {
            int cc = u * 8 + cc2;
            zs[cc][rr] = z[b * 262144 + cc * 1024 + hw0 + rr];
        }
    }

    // phase 1: per-row max of group top1s (= exact global row max); keep e[]
    unsigned long long e[16];
    unsigned m = 0;
#pragma unroll
    for (int g2 = 0; g2 < 16; ++g2) {
        e[g2] = gstats[(size_t)(gc * 16 + g2) * 16384u + (unsigned)(n0 + r)];
        m = umax_(m, (unsigned)(e[g2] >> 32));
    }
    pmax[gc][r] = m;
    if (t == 0) blkcnt = 0;
    __syncthreads();
    if (t < 32) {
        unsigned mm = 0;
#pragma unroll
        for (int g = 0; g < 8; ++g) mm = umax_(mm, pmax[g][t]);
        thrL[t] = (int)(mm >> 6) - MARGIN_INT;   // biased domain both sides
        bestL[t] = ~0ull;
    }
    __syncthreads();

    // phase 2: candidates = group top-1/top-2 entries >= threshold
    {
        int th = thrL[r];
#pragma unroll
        for (int g2 = 0; g2 < 16; ++g2) {
            unsigned p1 = (unsigned)(e[g2] >> 32), p2 = (unsigned)e[g2];
            unsigned kb = (unsigned)(gc * 16 + g2) * 64u;
            if ((int)(p1 >> 6) >= th) {
                unsigned pos = atomicAdd(&blkcnt, 1u);
                if (pos < 512u)
                    candL[pos] = ((unsigned)r << 13) | (kb + (p1 & 63u));
            }
            if ((int)(p2 >> 6) >= th) {
                unsigned pos = atomicAdd(&blkcnt, 1u);
                if (pos < 512u)
                    candL[pos] = ((unsigned)r << 13) | (kb + (p2 & 63u));
            }
        }
    }
    __syncthreads();
    int ns = (int)(blkcnt < 512u ? blkcnt : 512u);

    // rescore: barrier-free candidate loop against the staged zs tile
    for (int base = 0; base < ns; base += 256) {
        if (base + t < ns) {
            unsigned v = candL[base + t];
            int rr0 = v >> 13, k = v & 8191;
            float sacc = 0.f;
#pragma unroll 1
            for (int ch = 0; ch < 8; ++ch) {
                const float4* cbp = (const float4*)(cb + k * 256 + ch * 32);
                float4 A0 = cbp[0], A1 = cbp[1], A2 = cbp[2], A3 = cbp[3];
                float4 A4 = cbp[4], A5 = cbp[5], A6 = cbp[6], A7 = cbp[7];
                float Af[32] = {A0.x,A0.y,A0.z,A0.w, A1.x,A1.y,A1.z,A1.w,
                                A2.x,A2.y,A2.z,A2.w, A3.x,A3.y,A3.z,A3.w,
                                A4.x,A4.y,A4.z,A4.w, A5.x,A5.y,A5.z,A5.w,
                                A6.x,A6.y,A6.z,A6.w, A7.x,A7.y,A7.z,A7.w};
#pragma unroll
                for (int u = 0; u < 32; ++u)
                    sacc = __builtin_fmaf(zs[ch * 32 + u][rr0], Af[u], sacc);
            }
            float d = z2w[n0 + rr0] - 2.0f * sacc;   // single rounding, d > 0
            unsigned long long key =
                ((unsigned long long)__float_as_uint(d) << 32) | (unsigned)k;
            atomicMin(&bestL[rr0], key);
        }
    }
    __syncthreads();
    if (t < 32)
        out_idx[n0 + t] = (float)(unsigned)(bestL[t] & 0xFFFFFFFFu);

    // ---- fused scatter: gather 32 winning cb rows, write out k-coalesced --
    {
        const int c0 = t & 63;
        const int w0 = (t >> 6) * 8;
#pragma unroll
        for (int it = 0; it < 8; ++it) {
            int wr = w0 + it;
            int kk = (int)(unsigned)(bestL[wr] & 0xFFFFFFFFu);
            const float* src = cb + kk * 256 + c0;
            float* drow = tile + wr * 257 + c0;
            drow[0]   = src[0];
            drow[64]  = src[64];
            drow[128] = src[128];
            drow[192] = src[192];
        }
    }
    __syncthreads();

    float* obase = out + b * 262144 + j * 256;
    const int wv = t >> 3, cb8 = (t & 7) * 32;
#pragma unroll
    for (int it = 0; it < 32; ++it)     // it = i; lane = k (coalesced store)
        obase[it * 8192 + t] = tile[wv * 257 + cb8 + it];
}

// ---------------------------------------------------------------------------
// Loss (VALIDATED), block = (b, i): z read w-coalesced (staged), out re-read
// coalesced. loss += 1.25/N * sum((zp - zq)^2).
__global__ __launch_bounds__(256) void vq_loss(
        const float* __restrict__ z, const float* __restrict__ out,
        float* __restrict__ loss_out) {
    __shared__ float zs[256][33];
    __shared__ float wsum[4];

    const int t = threadIdx.x;
    const int b = blockIdx.x >> 5, i = blockIdx.x & 31;

#pragma unroll
    for (int it = 0; it < 32; ++it) {
        int k = it * 8 + (t >> 5);
        zs[k][t & 31] = z[b * 262144 + k * 1024 + i * 32 + (t & 31)];
    }
    __syncthreads();

    const float* ob = out + b * 262144 + i * 8192;
    float lsum = 0.f;
#pragma unroll 4
    for (int it = 0; it < 32; ++it) {   // it = j; lane = k
        float d = zs[t][it] - ob[it * 256 + t];
        lsum = __builtin_fmaf(d, d, lsum);
    }
#pragma unroll
    for (int off = 32; off >= 1; off >>= 1) lsum += __shfl_down(lsum, off, 64);
    int lane = t & 63, wv = t >> 6;
    if (lane == 0) wsum[wv] = lsum;
    __syncthreads();
    if (t == 0)
        atomicAdd(loss_out, (wsum[0] + wsum[1] + wsum[2] + wsum[3]) *
                            (1.25f / (float)NELEM));
}

// ---------------------------------------------------------------------------
extern "C" void kernel_launch(void* const* d_in, const int* in_sizes, int n_in,
                              void* d_out, int out_size, void* d_ws, size_t ws_size,
                              hipStream_t stream) {
    const float* z  = (const float*)d_in[0];
    const float* cb = (const float*)d_in[1];
    float* out = (float*)d_out;

    char* ws = (char*)d_ws;
    char* zbi8               = ws;                                   // 4 MB
    char* cbbi8              = ws + 4194304;                         // 2 MB
    unsigned long long* gstats = (unsigned long long*)(ws + 6291456); // 16 MB
    float* z2w               = (float*)(ws + 23068672);

    vq_prep<<<384, 256, 0, stream>>>(z, cb, z2w, zbi8, cbbi8, out + NELEM);

    vq_gemm<<<1024, 256, 0, stream>>>(zbi8, cbbi8, gstats);

    vq_finalize<<<512, 256, 0, stream>>>(z, cb, z2w, gstats,
                                         out, out + NELEM + 1);

    vq_loss<<<512, 256, 0, stream>>>(z, out, out + NELEM);
}